// Round 1
// baseline (2960.227 us; speedup 1.0000x reference)
//
#include <hip/hip_runtime.h>
#include <math.h>

#define NB 4
#define SEQ 4096
#define DM 512
#define NH 8
#define HD 64
#define UU 27
#define NIDX (SEQ*UU)   // 110592

typedef unsigned int u32;

__host__ __device__ inline u32 rotl32(u32 x, u32 r){ return (x<<r)|(x>>(32u-r)); }

// Exact JAX threefry2x32 block cipher.
__host__ __device__ inline void threefry2x32(u32 k0, u32 k1, u32 x0, u32 x1, u32* o0, u32* o1)
{
  u32 ks[3] = { k0, k1, k0 ^ k1 ^ 0x1BD11BDAu };
  x0 += ks[0]; x1 += ks[1];
  const u32 rotA[4] = {13u,15u,26u,6u};
  const u32 rotB[4] = {17u,29u,16u,24u};
  for (int i = 0; i < 5; i++) {
    const u32* rot = (i & 1) ? rotB : rotA;
    for (int j = 0; j < 4; j++) { x0 += x1; x1 = rotl32(x1, rot[j]); x1 ^= x0; }
    x0 += ks[(i+1)%3];
    x1 += ks[(i+2)%3] + (u32)(i+1);
  }
  *o0 = x0; *o1 = x1;
}

// Partitionable threefry stream: bits[i] = out0^out1 of threefry(k2, (0, i)); idx = bits & 4095.
__global__ __launch_bounds__(256) void gen_idx_kernel(u32 k2a, u32 k2b, int* __restrict__ idx)
{
  int i = blockIdx.x * 256 + threadIdx.x;
  if (i >= NIDX) return;
  u32 o0, o1;
  threefry2x32(k2a, k2b, 0u, (u32)i, &o0, &o1);
  idx[i] = (int)((o0 ^ o1) & (SEQ - 1));
}

// C(16384,512) = A(16384,512) @ W(512,512) + bias [+ resid], row-major, fp32.
// BM=BN=128, BK=16, 256 threads, 8x8 microtile.
__global__ __launch_bounds__(256) void gemm512(
    const float* __restrict__ A, const float* __restrict__ W,
    const float* __restrict__ bias, float* __restrict__ C,
    const float* __restrict__ resid, int rowJump)
{
  __shared__ float As[16][128];   // [k][m] (transposed store)
  __shared__ float Bs[16][128];   // [k][n]
  const int t  = threadIdx.x;
  const int rb = blockIdx.x * 128;
  const int cb = blockIdx.y * 128;
  const int ty = t >> 4, tx = t & 15;

  const int ar = t >> 2;          // 0..63
  const int ac = (t & 3) << 2;    // 0,4,8,12
  const int bk = t >> 5;          // 0..7
  const int bn = (t & 31) << 2;   // 0..124

  const float* Aptr  = A + (long)(rb + ar) * DM + ac;
  const float* Aptr2 = Aptr + (long)64 * DM;
  const float* Wptr  = W + (long)bk * DM + cb + bn;
  const float* Wptr2 = Wptr + (long)8 * DM;

  float acc[8][8];
  #pragma unroll
  for (int i = 0; i < 8; i++)
    #pragma unroll
    for (int j = 0; j < 8; j++) acc[i][j] = 0.f;

  for (int kk = 0; kk < DM; kk += 16) {
    float4 a0 = *(const float4*)(Aptr  + kk);
    float4 a1 = *(const float4*)(Aptr2 + kk);
    float4 b0 = *(const float4*)(Wptr  + (long)kk * DM);
    float4 b1 = *(const float4*)(Wptr2 + (long)kk * DM);
    __syncthreads();
    As[ac+0][ar]    = a0.x; As[ac+1][ar]    = a0.y; As[ac+2][ar]    = a0.z; As[ac+3][ar]    = a0.w;
    As[ac+0][ar+64] = a1.x; As[ac+1][ar+64] = a1.y; As[ac+2][ar+64] = a1.z; As[ac+3][ar+64] = a1.w;
    *(float4*)&Bs[bk][bn]   = b0;
    *(float4*)&Bs[bk+8][bn] = b1;
    __syncthreads();
    #pragma unroll
    for (int k = 0; k < 16; k++) {
      float4 x0 = *(const float4*)&As[k][ty*8];
      float4 x1 = *(const float4*)&As[k][ty*8+4];
      float4 y0 = *(const float4*)&Bs[k][tx*8];
      float4 y1 = *(const float4*)&Bs[k][tx*8+4];
      float av[8] = {x0.x,x0.y,x0.z,x0.w,x1.x,x1.y,x1.z,x1.w};
      float bv[8] = {y0.x,y0.y,y0.z,y0.w,y1.x,y1.y,y1.z,y1.w};
      #pragma unroll
      for (int i = 0; i < 8; i++)
        #pragma unroll
        for (int j = 0; j < 8; j++)
          acc[i][j] = fmaf(av[i], bv[j], acc[i][j]);
    }
  }

  float bvals[8];
  *(float4*)&bvals[0] = *(const float4*)&bias[cb + tx*8];
  *(float4*)&bvals[4] = *(const float4*)&bias[cb + tx*8 + 4];
  #pragma unroll
  for (int i = 0; i < 8; i++) {
    int r = rb + ty*8 + i;
    long off = (long)r * DM + (long)(r >> 12) * rowJump + cb + tx*8;
    float4 o0, o1;
    o0.x = acc[i][0] + bvals[0]; o0.y = acc[i][1] + bvals[1];
    o0.z = acc[i][2] + bvals[2]; o0.w = acc[i][3] + bvals[3];
    o1.x = acc[i][4] + bvals[4]; o1.y = acc[i][5] + bvals[5];
    o1.z = acc[i][6] + bvals[6]; o1.w = acc[i][7] + bvals[7];
    if (resid) {
      float4 r0 = *(const float4*)(resid + off);
      float4 r1 = *(const float4*)(resid + off + 4);
      o0.x += r0.x; o0.y += r0.y; o0.z += r0.z; o0.w += r0.w;
      o1.x += r1.x; o1.y += r1.y; o1.z += r1.z; o1.w += r1.w;
    }
    *(float4*)(C + off)     = o0;
    *(float4*)(C + off + 4) = o1;
  }
}

// M[b,h,l] = max_s(Q.Ksample) - sum_s(Q.Ksample)/SEQ. One wave per (b,h,l).
__global__ __launch_bounds__(256) void mscore_kernel(const float* __restrict__ Q, const float* __restrict__ K,
                                                     const int* __restrict__ idx, float* __restrict__ M)
{
  int g = blockIdx.x * 4 + (threadIdx.x >> 6);
  int lane = threadIdx.x & 63;
  int b = g >> 15;
  int h = (g >> 12) & 7;
  int l = g & (SEQ - 1);
  float qd = Q[((long)(b << 12) + l) * DM + h * HD + lane];
  const int* ip = idx + l * UU;
  float mx = -INFINITY, sm = 0.f;
  for (int s = 0; s < UU; s++) {
    int kl = ip[s];
    float v = qd * K[((long)(b << 12) + kl) * DM + h * HD + lane];
    #pragma unroll
    for (int m = 32; m; m >>= 1) v += __shfl_xor(v, m, 64);
    mx = fmaxf(mx, v);
    sm += v;
  }
  if (lane == 0) M[g] = mx - sm * (1.0f / (float)SEQ);
}

// Stable top-27 of 4096 per (b,h). Ties: lower index first (lax.top_k).
__global__ __launch_bounds__(256) void topk_kernel(const float* __restrict__ M, int* __restrict__ topidx)
{
  __shared__ float vals[SEQ];
  __shared__ float rv[256];
  __shared__ int   ri[256];
  const float* m = M + (long)blockIdx.x * SEQ;
  for (int i = threadIdx.x; i < SEQ; i += 256) vals[i] = m[i];
  __syncthreads();
  for (int it = 0; it < UU; it++) {
    float bv = -INFINITY; int bi = 0x7fffffff;
    for (int i = threadIdx.x; i < SEQ; i += 256) {
      float v = vals[i];
      if (v > bv) { bv = v; bi = i; }
    }
    rv[threadIdx.x] = bv; ri[threadIdx.x] = bi;
    __syncthreads();
    for (int s = 128; s > 0; s >>= 1) {
      if (threadIdx.x < s) {
        float ov = rv[threadIdx.x + s]; int oi = ri[threadIdx.x + s];
        if (ov > rv[threadIdx.x] || (ov == rv[threadIdx.x] && oi < ri[threadIdx.x])) {
          rv[threadIdx.x] = ov; ri[threadIdx.x] = oi;
        }
      }
      __syncthreads();
    }
    if (threadIdx.x == 0) { topidx[blockIdx.x * UU + it] = ri[0]; vals[ri[0]] = -INFINITY; }
    __syncthreads();
  }
}

// Column sums of V per batch (for V.mean), atomic partial sums.
__global__ __launch_bounds__(512) void vmean_partial(const float* __restrict__ V, float* __restrict__ vsum)
{
  int b = blockIdx.x >> 5, chunk = blockIdx.x & 31;
  int c = threadIdx.x;
  const float* p = V + ((long)b * SEQ + chunk * 128) * DM + c;
  float s = 0.f;
  for (int l = 0; l < 128; l++) s += p[(long)l * DM];
  atomicAdd(&vsum[b * DM + c], s);
}

// Full attention for the 27 selected queries. One block (4 waves) per (b,h,u).
__global__ __launch_bounds__(256) void attn_top(const float* __restrict__ Q, const float* __restrict__ K,
                                                const float* __restrict__ V, const int* __restrict__ topidx,
                                                float* __restrict__ out_top)
{
  __shared__ float sc[SEQ];
  __shared__ float wred[256];
  __shared__ float wmaxs[4], wsums[4];
  int g = blockIdx.x;                 // (b*NH+h)*UU + u
  int bh = g / UU;
  int b = bh >> 3, h = bh & 7;
  int w = threadIdx.x >> 6, lane = threadIdx.x & 63;
  int ql = topidx[g];
  float qd = Q[((long)(b << 12) + ql) * DM + h * HD + lane];
  float wmax = -INFINITY;
  for (int l = w; l < SEQ; l += 4) {
    float v = qd * K[((long)(b << 12) + l) * DM + h * HD + lane];
    #pragma unroll
    for (int m = 32; m; m >>= 1) v += __shfl_xor(v, m, 64);
    v *= 0.125f;                      // 1/sqrt(64)
    if (lane == 0) sc[l] = v;
    wmax = fmaxf(wmax, v);
  }
  if (lane == 0) wmaxs[w] = wmax;
  __syncthreads();
  float mx = fmaxf(fmaxf(wmaxs[0], wmaxs[1]), fmaxf(wmaxs[2], wmaxs[3]));
  float acc = 0.f, ps = 0.f;
  for (int l = w; l < SEQ; l += 4) {
    float p = expf(sc[l] - mx);
    ps += p;
    acc = fmaf(p, V[((long)(b << 12) + l) * DM + h * HD + lane], acc);
  }
  wred[w * 64 + lane] = acc;
  if (lane == 0) wsums[w] = ps;
  __syncthreads();
  if (threadIdx.x < 64) {
    float o = wred[lane] + wred[64 + lane] + wred[128 + lane] + wred[192 + lane];
    float s = wsums[0] + wsums[1] + wsums[2] + wsums[3];
    out_top[(long)g * HD + lane] = o / s;
  }
}

// ctx[b,l,:] = vsum[b,:]/SEQ (broadcast V-mean), float4.
__global__ __launch_bounds__(256) void ctx_fill(const float* __restrict__ vsum, float* __restrict__ ctx)
{
  long g = (long)blockIdx.x * 256 + threadIdx.x;   // over NB*SEQ*DM/4
  int b = (int)(g >> 19);
  int c4 = (int)(g & 127);
  float4 v = ((const float4*)vsum)[b * 128 + c4];
  const float s = 1.0f / (float)SEQ;
  v.x *= s; v.y *= s; v.z *= s; v.w *= s;
  ((float4*)ctx)[g] = v;
}

__global__ __launch_bounds__(64) void scatter_top(const float* __restrict__ out_top, const int* __restrict__ topidx,
                                                  float* __restrict__ ctx)
{
  int g = blockIdx.x;                 // (b*NH+h)*UU + u
  int bh = g / UU;
  int b = bh >> 3, h = bh & 7;
  int l = topidx[g];
  ctx[((long)(b << 12) + l) * DM + h * HD + threadIdx.x] = out_top[(long)g * HD + threadIdx.x];
}

// out[b, 4096+l, :] = xs[b, 4096+l, :] + xp2[b, l, :]
__global__ __launch_bounds__(256) void add_upper(const float* __restrict__ xs, const float* __restrict__ xp2,
                                                 float* __restrict__ out)
{
  long g = (long)blockIdx.x * 256 + threadIdx.x;   // over NB*SEQ*DM/4
  int b = (int)(g >> 19);
  long rem = g & 524287;
  float4 p = ((const float4*)xp2)[g];
  long o = ((long)b * 8192 + SEQ) * 128 + rem;
  float4 x = ((const float4*)xs)[o];
  x.x += p.x; x.y += p.y; x.z += p.z; x.w += p.w;
  ((float4*)out)[o] = x;
}

extern "C" void kernel_launch(void* const* d_in, const int* in_sizes, int n_in,
                              void* d_out, int out_size, void* d_ws, size_t ws_size,
                              hipStream_t stream)
{
  const float* xs  = (const float*)d_in[0];
  const float* xd  = (const float*)d_in[1];
  const float* xp  = (const float*)d_in[2];
  const float* w0q = (const float*)d_in[3];
  const float* w0k = (const float*)d_in[4];
  const float* w0v = (const float*)d_in[5];
  const float* w0o = (const float*)d_in[6];
  const float* b0q = (const float*)d_in[7];
  const float* b0k = (const float*)d_in[8];
  const float* b0v = (const float*)d_in[9];
  const float* b0o = (const float*)d_in[10];
  const float* w1q = (const float*)d_in[11];
  const float* w1k = (const float*)d_in[12];
  const float* w1v = (const float*)d_in[13];
  const float* w1o = (const float*)d_in[14];
  const float* b1q = (const float*)d_in[15];
  const float* b1k = (const float*)d_in[16];
  const float* b1v = (const float*)d_in[17];
  const float* b1o = (const float*)d_in[18];
  float* out = (float*)d_out;

  const long BIG = (long)NB * SEQ * DM;   // 8388608 floats
  float* A  = (float*)d_ws;
  float* Bb = A  + BIG;
  float* Cc = Bb + BIG;
  float* Dd = Cc + BIG;
  float* ex = Dd + BIG;
  int*   idxbuf = (int*)ex;
  float* Mbuf   = ex + NIDX;
  int*   topidx = (int*)(Mbuf + (long)NB * NH * SEQ);
  float* outtop = (float*)(topidx + NB * NH * UU);
  float* vsum   = outtop + NB * NH * UU * HD;

  dim3 gg(128, 4);
  u32 k2a, k2b;

  // ---------- layer 0: xp2 = attn_layer(q=xp; kv=xd), key 42 ----------
  threefry2x32(0u, 42u, 0u, 1u, &k2a, &k2b);   // foldlike split -> second key
  gen_idx_kernel<<<(NIDX + 255) / 256, 256, 0, stream>>>(k2a, k2b, idxbuf);
  gemm512<<<gg, 256, 0, stream>>>(xp, w0q, b0q, A,  nullptr, 0);
  gemm512<<<gg, 256, 0, stream>>>(xd, w0k, b0k, Bb, nullptr, 0);
  gemm512<<<gg, 256, 0, stream>>>(xd, w0v, b0v, Cc, nullptr, 0);
  mscore_kernel<<<NB * NH * SEQ / 4, 256, 0, stream>>>(A, Bb, idxbuf, Mbuf);
  topk_kernel<<<NB * NH, 256, 0, stream>>>(Mbuf, topidx);
  hipMemsetAsync(vsum, 0, NB * DM * sizeof(float), stream);
  vmean_partial<<<NB * 32, 512, 0, stream>>>(Cc, vsum);
  attn_top<<<NB * NH * UU, 256, 0, stream>>>(A, Bb, Cc, topidx, outtop);
  ctx_fill<<<8192, 256, 0, stream>>>(vsum, A);
  scatter_top<<<NB * NH * UU, 64, 0, stream>>>(outtop, topidx, A);
  gemm512<<<gg, 256, 0, stream>>>(A, w0o, b0o, Bb, nullptr, 0);   // xp2 -> Bb

  // ---------- layer 1: xd2 = attn_layer(q=xd; kv=xp2), key 43 ----------
  threefry2x32(0u, 43u, 0u, 1u, &k2a, &k2b);
  gen_idx_kernel<<<(NIDX + 255) / 256, 256, 0, stream>>>(k2a, k2b, idxbuf);
  gemm512<<<gg, 256, 0, stream>>>(xd, w1q, b1q, A,  nullptr, 0);
  gemm512<<<gg, 256, 0, stream>>>(Bb, w1k, b1k, Cc, nullptr, 0);
  gemm512<<<gg, 256, 0, stream>>>(Bb, w1v, b1v, Dd, nullptr, 0);
  mscore_kernel<<<NB * NH * SEQ / 4, 256, 0, stream>>>(A, Cc, idxbuf, Mbuf);
  topk_kernel<<<NB * NH, 256, 0, stream>>>(Mbuf, topidx);
  hipMemsetAsync(vsum, 0, NB * DM * sizeof(float), stream);
  vmean_partial<<<NB * 32, 512, 0, stream>>>(Dd, vsum);
  attn_top<<<NB * NH * UU, 256, 0, stream>>>(A, Cc, Dd, topidx, outtop);
  ctx_fill<<<8192, 256, 0, stream>>>(vsum, A);
  scatter_top<<<NB * NH * UU, 64, 0, stream>>>(outtop, topidx, A);
  // xd2 + xs -> out[:, :4096, :]  (rowJump skips the upper half per batch)
  gemm512<<<gg, 256, 0, stream>>>(A, w1o, b1o, out, xs, SEQ * DM);

  add_upper<<<8192, 256, 0, stream>>>(xs, Bb, out);
}

// Round 2
// 1641.023 us; speedup vs baseline: 1.8039x; 1.8039x over previous
//
#include <hip/hip_runtime.h>
#include <math.h>

#define NB 4
#define SEQ 4096
#define DM 512
#define NH 8
#define HD 64
#define UU 27
#define NIDX (SEQ*UU)   // 110592
#define NC 32           // key chunks per (b,h) in attn_part
#define CS 128          // chunk size (keys)
#define PSTRIDE 66      // per-(bh,chunk,u) partial: m, l, acc[64]

typedef unsigned int u32;

__host__ __device__ inline u32 rotl32(u32 x, u32 r){ return (x<<r)|(x>>(32u-r)); }

// Exact JAX threefry2x32 block cipher.
__host__ __device__ inline void threefry2x32(u32 k0, u32 k1, u32 x0, u32 x1, u32* o0, u32* o1)
{
  u32 ks[3] = { k0, k1, k0 ^ k1 ^ 0x1BD11BDAu };
  x0 += ks[0]; x1 += ks[1];
  const u32 rotA[4] = {13u,15u,26u,6u};
  const u32 rotB[4] = {17u,29u,16u,24u};
  for (int i = 0; i < 5; i++) {
    const u32* rot = (i & 1) ? rotB : rotA;
    for (int j = 0; j < 4; j++) { x0 += x1; x1 = rotl32(x1, rot[j]); x1 ^= x0; }
    x0 += ks[(i+1)%3];
    x1 += ks[(i+2)%3] + (u32)(i+1);
  }
  *o0 = x0; *o1 = x1;
}

// Partitionable threefry stream: bits[i] = out0^out1 of threefry(k2, (0, i)); idx = bits & 4095.
__global__ __launch_bounds__(256) void gen_idx_kernel(u32 k2a, u32 k2b, int* __restrict__ idx)
{
  int i = blockIdx.x * 256 + threadIdx.x;
  if (i >= NIDX) return;
  u32 o0, o1;
  threefry2x32(k2a, k2b, 0u, (u32)i, &o0, &o1);
  idx[i] = (int)((o0 ^ o1) & (SEQ - 1));
}

// C(16384,512) = A(16384,512) @ W(512,512) + bias [+ resid], row-major, fp32.
__global__ __launch_bounds__(256) void gemm512(
    const float* __restrict__ A, const float* __restrict__ W,
    const float* __restrict__ bias, float* __restrict__ C,
    const float* __restrict__ resid, int rowJump)
{
  __shared__ float As[16][128];   // [k][m] (transposed store)
  __shared__ float Bs[16][128];   // [k][n]
  const int t  = threadIdx.x;
  const int rb = blockIdx.x * 128;
  const int cb = blockIdx.y * 128;
  const int ty = t >> 4, tx = t & 15;

  const int ar = t >> 2;          // 0..63
  const int ac = (t & 3) << 2;    // 0,4,8,12
  const int bk = t >> 5;          // 0..7
  const int bn = (t & 31) << 2;   // 0..124

  const float* Aptr  = A + (long)(rb + ar) * DM + ac;
  const float* Aptr2 = Aptr + (long)64 * DM;
  const float* Wptr  = W + (long)bk * DM + cb + bn;
  const float* Wptr2 = Wptr + (long)8 * DM;

  float acc[8][8];
  #pragma unroll
  for (int i = 0; i < 8; i++)
    #pragma unroll
    for (int j = 0; j < 8; j++) acc[i][j] = 0.f;

  for (int kk = 0; kk < DM; kk += 16) {
    float4 a0 = *(const float4*)(Aptr  + kk);
    float4 a1 = *(const float4*)(Aptr2 + kk);
    float4 b0 = *(const float4*)(Wptr  + (long)kk * DM);
    float4 b1 = *(const float4*)(Wptr2 + (long)kk * DM);
    __syncthreads();
    As[ac+0][ar]    = a0.x; As[ac+1][ar]    = a0.y; As[ac+2][ar]    = a0.z; As[ac+3][ar]    = a0.w;
    As[ac+0][ar+64] = a1.x; As[ac+1][ar+64] = a1.y; As[ac+2][ar+64] = a1.z; As[ac+3][ar+64] = a1.w;
    *(float4*)&Bs[bk][bn]   = b0;
    *(float4*)&Bs[bk+8][bn] = b1;
    __syncthreads();
    #pragma unroll
    for (int k = 0; k < 16; k++) {
      float4 x0 = *(const float4*)&As[k][ty*8];
      float4 x1 = *(const float4*)&As[k][ty*8+4];
      float4 y0 = *(const float4*)&Bs[k][tx*8];
      float4 y1 = *(const float4*)&Bs[k][tx*8+4];
      float av[8] = {x0.x,x0.y,x0.z,x0.w,x1.x,x1.y,x1.z,x1.w};
      float bv[8] = {y0.x,y0.y,y0.z,y0.w,y1.x,y1.y,y1.z,y1.w};
      #pragma unroll
      for (int i = 0; i < 8; i++)
        #pragma unroll
        for (int j = 0; j < 8; j++)
          acc[i][j] = fmaf(av[i], bv[j], acc[i][j]);
    }
  }

  float bvals[8];
  *(float4*)&bvals[0] = *(const float4*)&bias[cb + tx*8];
  *(float4*)&bvals[4] = *(const float4*)&bias[cb + tx*8 + 4];
  #pragma unroll
  for (int i = 0; i < 8; i++) {
    int r = rb + ty*8 + i;
    long off = (long)r * DM + (long)(r >> 12) * rowJump + cb + tx*8;
    float4 o0, o1;
    o0.x = acc[i][0] + bvals[0]; o0.y = acc[i][1] + bvals[1];
    o0.z = acc[i][2] + bvals[2]; o0.w = acc[i][3] + bvals[3];
    o1.x = acc[i][4] + bvals[4]; o1.y = acc[i][5] + bvals[5];
    o1.z = acc[i][6] + bvals[6]; o1.w = acc[i][7] + bvals[7];
    if (resid) {
      float4 r0 = *(const float4*)(resid + off);
      float4 r1 = *(const float4*)(resid + off + 4);
      o0.x += r0.x; o0.y += r0.y; o0.z += r0.z; o0.w += r0.w;
      o1.x += r1.x; o1.y += r1.y; o1.z += r1.z; o1.w += r1.w;
    }
    *(float4*)(C + off)     = o0;
    *(float4*)(C + off + 4) = o1;
  }
}

// M[b,h,l] = max_s(Q.Ksample) - sum_s(Q.Ksample)/SEQ. One wave per (b,h,l).
__global__ __launch_bounds__(256) void mscore_kernel(const float* __restrict__ Q, const float* __restrict__ K,
                                                     const int* __restrict__ idx, float* __restrict__ M)
{
  int g = blockIdx.x * 4 + (threadIdx.x >> 6);
  int lane = threadIdx.x & 63;
  int b = g >> 15;
  int h = (g >> 12) & 7;
  int l = g & (SEQ - 1);
  float qd = Q[((long)(b << 12) + l) * DM + h * HD + lane];
  const int* ip = idx + l * UU;
  float mx = -INFINITY, sm = 0.f;
  for (int s = 0; s < UU; s++) {
    int kl = ip[s];
    float v = qd * K[((long)(b << 12) + kl) * DM + h * HD + lane];
    #pragma unroll
    for (int m = 32; m; m >>= 1) v += __shfl_xor(v, m, 64);
    mx = fmaxf(mx, v);
    sm += v;
  }
  if (lane == 0) M[g] = mx - sm * (1.0f / (float)SEQ);
}

// Stable top-27 of 4096 per (b,h). Ties: lower index first (lax.top_k).
__global__ __launch_bounds__(256) void topk_kernel(const float* __restrict__ M, int* __restrict__ topidx)
{
  __shared__ float vals[SEQ];
  __shared__ float rv[256];
  __shared__ int   ri[256];
  const float* m = M + (long)blockIdx.x * SEQ;
  for (int i = threadIdx.x; i < SEQ; i += 256) vals[i] = m[i];
  __syncthreads();
  for (int it = 0; it < UU; it++) {
    float bv = -INFINITY; int bi = 0x7fffffff;
    for (int i = threadIdx.x; i < SEQ; i += 256) {
      float v = vals[i];
      if (v > bv) { bv = v; bi = i; }
    }
    rv[threadIdx.x] = bv; ri[threadIdx.x] = bi;
    __syncthreads();
    for (int s = 128; s > 0; s >>= 1) {
      if (threadIdx.x < s) {
        float ov = rv[threadIdx.x + s]; int oi = ri[threadIdx.x + s];
        if (ov > rv[threadIdx.x] || (ov == rv[threadIdx.x] && oi < ri[threadIdx.x])) {
          rv[threadIdx.x] = ov; ri[threadIdx.x] = oi;
        }
      }
      __syncthreads();
    }
    if (threadIdx.x == 0) { topidx[blockIdx.x * UU + it] = ri[0]; vals[ri[0]] = -INFINITY; }
    __syncthreads();
  }
}

// Column sums of V per batch (for V.mean), atomic partial sums.
__global__ __launch_bounds__(512) void vmean_partial(const float* __restrict__ V, float* __restrict__ vsum)
{
  int b = blockIdx.x >> 5, chunk = blockIdx.x & 31;
  int c = threadIdx.x;
  const float* p = V + ((long)b * SEQ + chunk * 128) * DM + c;
  float s = 0.f;
  for (int l = 0; l < 128; l++) s += p[(long)l * DM];
  atomicAdd(&vsum[b * DM + c], s);
}

// Flash-style chunked attention for the 27 selected queries.
// grid (bh=32, chunk=32), 256 threads. Emits per-chunk (m, l, acc[64]) partials.
__global__ __launch_bounds__(256) void attn_part(const float* __restrict__ Q, const float* __restrict__ K,
                                                 const float* __restrict__ V, const int* __restrict__ topidx,
                                                 float* __restrict__ partial)
{
  __shared__ float Qs[UU][HD];      // 6.9 KB
  __shared__ float S[UU][CS];       // 13.8 KB, scores -> P
  __shared__ float Vt[CS][HD];      // 32 KB
  __shared__ float m_s[UU], l_s[UU];

  const int t = threadIdx.x;
  const int bh = blockIdx.x;
  const int chunk = blockIdx.y;
  const int b = bh >> 3, h = bh & 7;
  const long kbase = ((long)(b << 12) + chunk * CS) * DM + h * HD;
  const int* tp = topidx + bh * UU;

  // stage Q_sel (gather) and V tile
  for (int i = t; i < UU * HD; i += 256) {
    int u = i >> 6, d = i & 63;
    Qs[u][d] = Q[((long)(b << 12) + tp[u]) * DM + h * HD + d];
  }
  for (int i = t; i < CS * (HD / 4); i += 256) {
    int row = i >> 4, c4 = (i & 15) << 2;
    *(float4*)&Vt[row][c4] = *(const float4*)(V + kbase + (long)row * DM + c4);
  }
  __syncthreads();

  // phase 1: scores. Thread pair (l, half) — K row half in regs, Q broadcast from LDS.
  {
    const int l = t >> 1, half = t & 1, d0 = half * 32;
    const float* kp = K + kbase + (long)l * DM + d0;
    float4 kr[8];
    #pragma unroll
    for (int j = 0; j < 8; j++) kr[j] = *(const float4*)(kp + j * 4);
    #pragma unroll 1
    for (int u = 0; u < UU; u++) {
      const float4* qf = (const float4*)&Qs[u][d0];
      float dot = 0.f;
      #pragma unroll
      for (int j = 0; j < 8; j++) {
        float4 q = qf[j];
        dot = fmaf(q.x, kr[j].x, dot); dot = fmaf(q.y, kr[j].y, dot);
        dot = fmaf(q.z, kr[j].z, dot); dot = fmaf(q.w, kr[j].w, dot);
      }
      float tot = dot + __shfl_xor(dot, 1, 64);
      if (half == 0) S[u][l] = tot * 0.125f;   // 1/sqrt(64)
    }
  }
  __syncthreads();

  // phase 2: per-u chunk softmax partial (max + expsum), P written back to S.
  {
    const int u = t >> 3, il = t & 7;
    if (u < UU) {
      float mx = -INFINITY;
      for (int l = il; l < CS; l += 8) mx = fmaxf(mx, S[u][l]);
      #pragma unroll
      for (int m = 1; m < 8; m <<= 1) mx = fmaxf(mx, __shfl_xor(mx, m, 64));
      float ps = 0.f;
      for (int l = il; l < CS; l += 8) {
        float e = expf(S[u][l] - mx);
        S[u][l] = e;
        ps += e;
      }
      #pragma unroll
      for (int m = 1; m < 8; m <<= 1) ps += __shfl_xor(ps, m, 64);
      if (il == 0) { m_s[u] = mx; l_s[u] = ps; }
    }
  }
  __syncthreads();

  // phase 3: PV accumulate + write partials.
  {
    const int d = t & 63, g = t >> 6;
    for (int u = g; u < UU; u += 4) {
      float acc = 0.f;
      #pragma unroll 4
      for (int l = 0; l < CS; l += 4) {
        float4 p4 = *(const float4*)&S[u][l];
        acc = fmaf(p4.x, Vt[l][d],     acc);
        acc = fmaf(p4.y, Vt[l + 1][d], acc);
        acc = fmaf(p4.z, Vt[l + 2][d], acc);
        acc = fmaf(p4.w, Vt[l + 3][d], acc);
      }
      float* pp = partial + (((long)bh * NC + chunk) * UU + u) * PSTRIDE;
      pp[2 + d] = acc;
      if (d == 0) { pp[0] = m_s[u]; pp[1] = l_s[u]; }
    }
  }
}

// Merge the NC chunk partials per (bh,u) and scatter into ctx at the top-idx row.
__global__ __launch_bounds__(64) void attn_merge(const float* __restrict__ partial, const int* __restrict__ topidx,
                                                 float* __restrict__ ctx)
{
  int g = blockIdx.x;          // bh*UU + u
  int bh = g / UU, u = g % UU;
  int b = bh >> 3, h = bh & 7;
  int d = threadIdx.x;
  float M = -INFINITY, S = 0.f, acc = 0.f;
  for (int c = 0; c < NC; c++) {
    const float* pp = partial + (((long)bh * NC + c) * UU + u) * PSTRIDE;
    float mc = pp[0], sc = pp[1], a = pp[2 + d];
    if (mc > M) {
      float r = expf(M - mc);
      acc *= r; S *= r; M = mc;
    }
    float w = expf(mc - M);
    acc = fmaf(a, w, acc);
    S = fmaf(sc, w, S);
  }
  int ql = topidx[g];
  ctx[((long)(b << 12) + ql) * DM + h * HD + d] = acc / S;
}

// ctx[b,l,:] = vsum[b,:]/SEQ (broadcast V-mean), float4.
__global__ __launch_bounds__(256) void ctx_fill(const float* __restrict__ vsum, float* __restrict__ ctx)
{
  long g = (long)blockIdx.x * 256 + threadIdx.x;   // over NB*SEQ*DM/4
  int b = (int)(g >> 19);
  int c4 = (int)(g & 127);
  float4 v = ((const float4*)vsum)[b * 128 + c4];
  const float s = 1.0f / (float)SEQ;
  v.x *= s; v.y *= s; v.z *= s; v.w *= s;
  ((float4*)ctx)[g] = v;
}

// out[b, 4096+l, :] = xs[b, 4096+l, :] + xp2[b, l, :]
__global__ __launch_bounds__(256) void add_upper(const float* __restrict__ xs, const float* __restrict__ xp2,
                                                 float* __restrict__ out)
{
  long g = (long)blockIdx.x * 256 + threadIdx.x;   // over NB*SEQ*DM/4
  int b = (int)(g >> 19);
  long rem = g & 524287;
  float4 p = ((const float4*)xp2)[g];
  long o = ((long)b * 8192 + SEQ) * 128 + rem;
  float4 x = ((const float4*)xs)[o];
  x.x += p.x; x.y += p.y; x.z += p.z; x.w += p.w;
  ((float4*)out)[o] = x;
}

extern "C" void kernel_launch(void* const* d_in, const int* in_sizes, int n_in,
                              void* d_out, int out_size, void* d_ws, size_t ws_size,
                              hipStream_t stream)
{
  const float* xs  = (const float*)d_in[0];
  const float* xd  = (const float*)d_in[1];
  const float* xp  = (const float*)d_in[2];
  const float* w0q = (const float*)d_in[3];
  const float* w0k = (const float*)d_in[4];
  const float* w0v = (const float*)d_in[5];
  const float* w0o = (const float*)d_in[6];
  const float* b0q = (const float*)d_in[7];
  const float* b0k = (const float*)d_in[8];
  const float* b0v = (const float*)d_in[9];
  const float* b0o = (const float*)d_in[10];
  const float* w1q = (const float*)d_in[11];
  const float* w1k = (const float*)d_in[12];
  const float* w1v = (const float*)d_in[13];
  const float* w1o = (const float*)d_in[14];
  const float* b1q = (const float*)d_in[15];
  const float* b1k = (const float*)d_in[16];
  const float* b1v = (const float*)d_in[17];
  const float* b1o = (const float*)d_in[18];
  float* out = (float*)d_out;

  const long BIG = (long)NB * SEQ * DM;   // 8388608 floats
  float* A  = (float*)d_ws;
  float* Bb = A  + BIG;
  float* Cc = Bb + BIG;
  float* Dd = Cc + BIG;
  float* ex = Dd + BIG;
  int*   idxbuf = (int*)ex;
  float* Mbuf   = ex + NIDX;
  int*   topidx = (int*)(Mbuf + (long)NB * NH * SEQ);
  float* vsum   = (float*)(topidx + NB * NH * UU);

  dim3 gg(128, 4);
  dim3 ag(NB * NH, NC);
  u32 k2a, k2b;

  // ---------- layer 0: xp2 = attn_layer(q=xp; kv=xd), key 42 ----------
  threefry2x32(0u, 42u, 0u, 1u, &k2a, &k2b);
  gen_idx_kernel<<<(NIDX + 255) / 256, 256, 0, stream>>>(k2a, k2b, idxbuf);
  gemm512<<<gg, 256, 0, stream>>>(xp, w0q, b0q, A,  nullptr, 0);
  gemm512<<<gg, 256, 0, stream>>>(xd, w0k, b0k, Bb, nullptr, 0);
  gemm512<<<gg, 256, 0, stream>>>(xd, w0v, b0v, Cc, nullptr, 0);
  mscore_kernel<<<NB * NH * SEQ / 4, 256, 0, stream>>>(A, Bb, idxbuf, Mbuf);
  topk_kernel<<<NB * NH, 256, 0, stream>>>(Mbuf, topidx);
  hipMemsetAsync(vsum, 0, NB * DM * sizeof(float), stream);
  vmean_partial<<<NB * 32, 512, 0, stream>>>(Cc, vsum);
  attn_part<<<ag, 256, 0, stream>>>(A, Bb, Cc, topidx, Dd);   // partials in Dd (free in layer 0)
  ctx_fill<<<8192, 256, 0, stream>>>(vsum, A);
  attn_merge<<<NB * NH * UU, 64, 0, stream>>>(Dd, topidx, A);
  gemm512<<<gg, 256, 0, stream>>>(A, w0o, b0o, Bb, nullptr, 0);   // xp2 -> Bb
  add_upper<<<8192, 256, 0, stream>>>(xs, Bb, out);               // upper half done now

  // ---------- layer 1: xd2 = attn_layer(q=xd; kv=xp2), key 43 ----------
  threefry2x32(0u, 43u, 0u, 1u, &k2a, &k2b);
  gen_idx_kernel<<<(NIDX + 255) / 256, 256, 0, stream>>>(k2a, k2b, idxbuf);
  gemm512<<<gg, 256, 0, stream>>>(xd, w1q, b1q, A,  nullptr, 0);
  gemm512<<<gg, 256, 0, stream>>>(Bb, w1k, b1k, Cc, nullptr, 0);
  gemm512<<<gg, 256, 0, stream>>>(Bb, w1v, b1v, Dd, nullptr, 0);
  mscore_kernel<<<NB * NH * SEQ / 4, 256, 0, stream>>>(A, Cc, idxbuf, Mbuf);
  topk_kernel<<<NB * NH, 256, 0, stream>>>(Mbuf, topidx);
  hipMemsetAsync(vsum, 0, NB * DM * sizeof(float), stream);
  vmean_partial<<<NB * 32, 512, 0, stream>>>(Dd, vsum);
  attn_part<<<ag, 256, 0, stream>>>(A, Cc, Dd, topidx, Bb);   // partials in Bb (xp2 consumed)
  ctx_fill<<<8192, 256, 0, stream>>>(vsum, A);
  attn_merge<<<NB * NH * UU, 64, 0, stream>>>(Bb, topidx, A);
  // xd2 + xs -> out[:, :4096, :]  (rowJump skips the upper half per batch)
  gemm512<<<gg, 256, 0, stream>>>(A, w1o, b1o, out, xs, SEQ * DM);
}

// Round 3
// 1422.741 us; speedup vs baseline: 2.0807x; 1.1534x over previous
//
#include <hip/hip_runtime.h>
#include <math.h>

#define NB 4
#define SEQ 4096
#define DM 512
#define NH 8
#define HD 64
#define UU 27
#define NIDX (SEQ*UU)   // 110592
#define NC 32           // key chunks per (b,h) in attn_part
#define CS 128          // chunk size (keys)
#define PSTRIDE 66      // per-(bh,chunk,u) partial: m, l, acc[64]

typedef unsigned int u32;

__host__ __device__ inline u32 rotl32(u32 x, u32 r){ return (x<<r)|(x>>(32u-r)); }

// Exact JAX threefry2x32 block cipher.
__host__ __device__ inline void threefry2x32(u32 k0, u32 k1, u32 x0, u32 x1, u32* o0, u32* o1)
{
  u32 ks[3] = { k0, k1, k0 ^ k1 ^ 0x1BD11BDAu };
  x0 += ks[0]; x1 += ks[1];
  const u32 rotA[4] = {13u,15u,26u,6u};
  const u32 rotB[4] = {17u,29u,16u,24u};
  for (int i = 0; i < 5; i++) {
    const u32* rot = (i & 1) ? rotB : rotA;
    for (int j = 0; j < 4; j++) { x0 += x1; x1 = rotl32(x1, rot[j]); x1 ^= x0; }
    x0 += ks[(i+1)%3];
    x1 += ks[(i+2)%3] + (u32)(i+1);
  }
  *o0 = x0; *o1 = x1;
}

// Partitionable threefry stream: bits[i] = out0^out1 of threefry(k2, (0, i)); idx = bits & 4095.
__global__ __launch_bounds__(256) void gen_idx_kernel(u32 k2a, u32 k2b, int* __restrict__ idx)
{
  int i = blockIdx.x * 256 + threadIdx.x;
  if (i >= NIDX) return;
  u32 o0, o1;
  threefry2x32(k2a, k2b, 0u, (u32)i, &o0, &o1);
  idx[i] = (int)((o0 ^ o1) & (SEQ - 1));
}

// C(16384,512) = A(16384,512) @ W(512,512) + bias [+ resid], row-major, fp32.
__global__ __launch_bounds__(256) void gemm512(
    const float* __restrict__ A, const float* __restrict__ W,
    const float* __restrict__ bias, float* __restrict__ C,
    const float* __restrict__ resid, int rowJump)
{
  __shared__ float As[16][128];   // [k][m] (transposed store)
  __shared__ float Bs[16][128];   // [k][n]
  const int t  = threadIdx.x;
  const int rb = blockIdx.x * 128;
  const int cb = blockIdx.y * 128;
  const int ty = t >> 4, tx = t & 15;

  const int ar = t >> 2;          // 0..63
  const int ac = (t & 3) << 2;    // 0,4,8,12
  const int bk = t >> 5;          // 0..7
  const int bn = (t & 31) << 2;   // 0..124

  const float* Aptr  = A + (long)(rb + ar) * DM + ac;
  const float* Aptr2 = Aptr + (long)64 * DM;
  const float* Wptr  = W + (long)bk * DM + cb + bn;
  const float* Wptr2 = Wptr + (long)8 * DM;

  float acc[8][8];
  #pragma unroll
  for (int i = 0; i < 8; i++)
    #pragma unroll
    for (int j = 0; j < 8; j++) acc[i][j] = 0.f;

  for (int kk = 0; kk < DM; kk += 16) {
    float4 a0 = *(const float4*)(Aptr  + kk);
    float4 a1 = *(const float4*)(Aptr2 + kk);
    float4 b0 = *(const float4*)(Wptr  + (long)kk * DM);
    float4 b1 = *(const float4*)(Wptr2 + (long)kk * DM);
    __syncthreads();
    As[ac+0][ar]    = a0.x; As[ac+1][ar]    = a0.y; As[ac+2][ar]    = a0.z; As[ac+3][ar]    = a0.w;
    As[ac+0][ar+64] = a1.x; As[ac+1][ar+64] = a1.y; As[ac+2][ar+64] = a1.z; As[ac+3][ar+64] = a1.w;
    *(float4*)&Bs[bk][bn]   = b0;
    *(float4*)&Bs[bk+8][bn] = b1;
    __syncthreads();
    #pragma unroll
    for (int k = 0; k < 16; k++) {
      float4 x0 = *(const float4*)&As[k][ty*8];
      float4 x1 = *(const float4*)&As[k][ty*8+4];
      float4 y0 = *(const float4*)&Bs[k][tx*8];
      float4 y1 = *(const float4*)&Bs[k][tx*8+4];
      float av[8] = {x0.x,x0.y,x0.z,x0.w,x1.x,x1.y,x1.z,x1.w};
      float bv[8] = {y0.x,y0.y,y0.z,y0.w,y1.x,y1.y,y1.z,y1.w};
      #pragma unroll
      for (int i = 0; i < 8; i++)
        #pragma unroll
        for (int j = 0; j < 8; j++)
          acc[i][j] = fmaf(av[i], bv[j], acc[i][j]);
    }
  }

  float bvals[8];
  *(float4*)&bvals[0] = *(const float4*)&bias[cb + tx*8];
  *(float4*)&bvals[4] = *(const float4*)&bias[cb + tx*8 + 4];
  #pragma unroll
  for (int i = 0; i < 8; i++) {
    int r = rb + ty*8 + i;
    long off = (long)r * DM + (long)(r >> 12) * rowJump + cb + tx*8;
    float4 o0, o1;
    o0.x = acc[i][0] + bvals[0]; o0.y = acc[i][1] + bvals[1];
    o0.z = acc[i][2] + bvals[2]; o0.w = acc[i][3] + bvals[3];
    o1.x = acc[i][4] + bvals[4]; o1.y = acc[i][5] + bvals[5];
    o1.z = acc[i][6] + bvals[6]; o1.w = acc[i][7] + bvals[7];
    if (resid) {
      float4 r0 = *(const float4*)(resid + off);
      float4 r1 = *(const float4*)(resid + off + 4);
      o0.x += r0.x; o0.y += r0.y; o0.z += r0.z; o0.w += r0.w;
      o1.x += r1.x; o1.y += r1.y; o1.z += r1.z; o1.w += r1.w;
    }
    *(float4*)(C + off)     = o0;
    *(float4*)(C + off + 4) = o1;
  }
}

// M[b,h,l] for ALL 8 heads by one wave per (b,l): lane = h*8+j, 8 dims/lane.
// idx[l,*] is head/batch independent -> one coalesced 2KB K-row read serves 8 heads.
__global__ __launch_bounds__(256) void mscore_kernel(const float* __restrict__ Q, const float* __restrict__ K,
                                                     const int* __restrict__ idx, float* __restrict__ M)
{
  const int wl = threadIdx.x >> 6, lane = threadIdx.x & 63;
  const int bl = blockIdx.x * 4 + wl;       // b*4096 + l
  const int b = bl >> 12, l = bl & (SEQ - 1);

  const float4* qp = (const float4*)(Q + (long)bl * DM + lane * 8);
  float4 q0 = qp[0], q1 = qp[1];

  const int* ip = idx + l * UU;
  int idxv = ip[lane < UU ? lane : 0];      // 27 idx values live in lanes 0..26

  const float* kb = K + ((long)b << 12) * DM + lane * 8;
  float mx = -INFINITY, sm = 0.f;
  #pragma unroll 4
  for (int s = 0; s < UU; s++) {
    int kl = __shfl(idxv, s, 64);
    const float4* kp = (const float4*)(kb + (long)kl * DM);
    float4 k0 = kp[0], k1 = kp[1];
    float dot;
    dot = q0.x * k0.x;
    dot = fmaf(q0.y, k0.y, dot); dot = fmaf(q0.z, k0.z, dot); dot = fmaf(q0.w, k0.w, dot);
    dot = fmaf(q1.x, k1.x, dot); dot = fmaf(q1.y, k1.y, dot);
    dot = fmaf(q1.z, k1.z, dot); dot = fmaf(q1.w, k1.w, dot);
    // reduce within the 8-lane head group
    dot += __shfl_xor(dot, 1, 64);
    dot += __shfl_xor(dot, 2, 64);
    dot += __shfl_xor(dot, 4, 64);
    mx = fmaxf(mx, dot);
    sm += dot;
  }
  if ((lane & 7) == 0) {
    int h = lane >> 3;
    M[(((long)b * NH + h) << 12) + l] = mx - sm * (1.0f / (float)SEQ);
  }
}

// Stable top-27 of 4096 per (b,h). Ties: lower index first (lax.top_k).
__global__ __launch_bounds__(256) void topk_kernel(const float* __restrict__ M, int* __restrict__ topidx)
{
  __shared__ float vals[SEQ];
  __shared__ float rv[256];
  __shared__ int   ri[256];
  const float* m = M + (long)blockIdx.x * SEQ;
  for (int i = threadIdx.x; i < SEQ; i += 256) vals[i] = m[i];
  __syncthreads();
  for (int it = 0; it < UU; it++) {
    float bv = -INFINITY; int bi = 0x7fffffff;
    for (int i = threadIdx.x; i < SEQ; i += 256) {
      float v = vals[i];
      if (v > bv) { bv = v; bi = i; }
    }
    rv[threadIdx.x] = bv; ri[threadIdx.x] = bi;
    __syncthreads();
    for (int s = 128; s > 0; s >>= 1) {
      if (threadIdx.x < s) {
        float ov = rv[threadIdx.x + s]; int oi = ri[threadIdx.x + s];
        if (ov > rv[threadIdx.x] || (ov == rv[threadIdx.x] && oi < ri[threadIdx.x])) {
          rv[threadIdx.x] = ov; ri[threadIdx.x] = oi;
        }
      }
      __syncthreads();
    }
    if (threadIdx.x == 0) { topidx[blockIdx.x * UU + it] = ri[0]; vals[ri[0]] = -INFINITY; }
    __syncthreads();
  }
}

// Column sums of V per batch (for V.mean), atomic partial sums.
__global__ __launch_bounds__(512) void vmean_partial(const float* __restrict__ V, float* __restrict__ vsum)
{
  int b = blockIdx.x >> 5, chunk = blockIdx.x & 31;
  int c = threadIdx.x;
  const float* p = V + ((long)b * SEQ + chunk * 128) * DM + c;
  float s = 0.f;
  for (int l = 0; l < 128; l++) s += p[(long)l * DM];
  atomicAdd(&vsum[b * DM + c], s);
}

// Flash-style chunked attention for the 27 selected queries.
// grid (bh=32, chunk=32), 256 threads. Emits per-chunk (m, l, acc[64]) partials.
__global__ __launch_bounds__(256) void attn_part(const float* __restrict__ Q, const float* __restrict__ K,
                                                 const float* __restrict__ V, const int* __restrict__ topidx,
                                                 float* __restrict__ partial)
{
  __shared__ float Qs[UU][HD];      // 6.9 KB
  __shared__ float S[UU][CS];       // 13.8 KB, scores -> P
  __shared__ float Vt[CS][HD];      // 32 KB
  __shared__ float m_s[UU], l_s[UU];

  const int t = threadIdx.x;
  const int bh = blockIdx.x;
  const int chunk = blockIdx.y;
  const int b = bh >> 3, h = bh & 7;
  const long kbase = ((long)(b << 12) + chunk * CS) * DM + h * HD;
  const int* tp = topidx + bh * UU;

  // stage Q_sel (gather) and V tile
  for (int i = t; i < UU * HD; i += 256) {
    int u = i >> 6, d = i & 63;
    Qs[u][d] = Q[((long)(b << 12) + tp[u]) * DM + h * HD + d];
  }
  for (int i = t; i < CS * (HD / 4); i += 256) {
    int row = i >> 4, c4 = (i & 15) << 2;
    *(float4*)&Vt[row][c4] = *(const float4*)(V + kbase + (long)row * DM + c4);
  }
  __syncthreads();

  // phase 1: scores. Thread pair (l, half) — K row half in regs, Q broadcast from LDS.
  {
    const int l = t >> 1, half = t & 1, d0 = half * 32;
    const float* kp = K + kbase + (long)l * DM + d0;
    float4 kr[8];
    #pragma unroll
    for (int j = 0; j < 8; j++) kr[j] = *(const float4*)(kp + j * 4);
    #pragma unroll 1
    for (int u = 0; u < UU; u++) {
      const float4* qf = (const float4*)&Qs[u][d0];
      float dot = 0.f;
      #pragma unroll
      for (int j = 0; j < 8; j++) {
        float4 q = qf[j];
        dot = fmaf(q.x, kr[j].x, dot); dot = fmaf(q.y, kr[j].y, dot);
        dot = fmaf(q.z, kr[j].z, dot); dot = fmaf(q.w, kr[j].w, dot);
      }
      float tot = dot + __shfl_xor(dot, 1, 64);
      if (half == 0) S[u][l] = tot * 0.125f;   // 1/sqrt(64)
    }
  }
  __syncthreads();

  // phase 2: per-u chunk softmax partial (max + expsum), P written back to S.
  {
    const int u = t >> 3, il = t & 7;
    if (u < UU) {
      float mx = -INFINITY;
      for (int l = il; l < CS; l += 8) mx = fmaxf(mx, S[u][l]);
      #pragma unroll
      for (int m = 1; m < 8; m <<= 1) mx = fmaxf(mx, __shfl_xor(mx, m, 64));
      float ps = 0.f;
      for (int l = il; l < CS; l += 8) {
        float e = expf(S[u][l] - mx);
        S[u][l] = e;
        ps += e;
      }
      #pragma unroll
      for (int m = 1; m < 8; m <<= 1) ps += __shfl_xor(ps, m, 64);
      if (il == 0) { m_s[u] = mx; l_s[u] = ps; }
    }
  }
  __syncthreads();

  // phase 3: PV accumulate + write partials.
  {
    const int d = t & 63, g = t >> 6;
    for (int u = g; u < UU; u += 4) {
      float acc = 0.f;
      #pragma unroll 4
      for (int l = 0; l < CS; l += 4) {
        float4 p4 = *(const float4*)&S[u][l];
        acc = fmaf(p4.x, Vt[l][d],     acc);
        acc = fmaf(p4.y, Vt[l + 1][d], acc);
        acc = fmaf(p4.z, Vt[l + 2][d], acc);
        acc = fmaf(p4.w, Vt[l + 3][d], acc);
      }
      float* pp = partial + (((long)bh * NC + chunk) * UU + u) * PSTRIDE;
      pp[2 + d] = acc;
      if (d == 0) { pp[0] = m_s[u]; pp[1] = l_s[u]; }
    }
  }
}

// Merge the NC chunk partials per (bh,u) and scatter into ctx at the top-idx row.
__global__ __launch_bounds__(64) void attn_merge(const float* __restrict__ partial, const int* __restrict__ topidx,
                                                 float* __restrict__ ctx)
{
  int g = blockIdx.x;          // bh*UU + u
  int bh = g / UU, u = g % UU;
  int b = bh >> 3, h = bh & 7;
  int d = threadIdx.x;
  float M = -INFINITY, S = 0.f, acc = 0.f;
  for (int c = 0; c < NC; c++) {
    const float* pp = partial + (((long)bh * NC + c) * UU + u) * PSTRIDE;
    float mc = pp[0], sc = pp[1], a = pp[2 + d];
    if (mc > M) {
      float r = expf(M - mc);
      acc *= r; S *= r; M = mc;
    }
    float w = expf(mc - M);
    acc = fmaf(a, w, acc);
    S = fmaf(sc, w, S);
  }
  int ql = topidx[g];
  ctx[((long)(b << 12) + ql) * DM + h * HD + d] = acc / S;
}

// ctx[b,l,:] = vsum[b,:]/SEQ (broadcast V-mean), float4.
__global__ __launch_bounds__(256) void ctx_fill(const float* __restrict__ vsum, float* __restrict__ ctx)
{
  long g = (long)blockIdx.x * 256 + threadIdx.x;   // over NB*SEQ*DM/4
  int b = (int)(g >> 19);
  int c4 = (int)(g & 127);
  float4 v = ((const float4*)vsum)[b * 128 + c4];
  const float s = 1.0f / (float)SEQ;
  v.x *= s; v.y *= s; v.z *= s; v.w *= s;
  ((float4*)ctx)[g] = v;
}

// out[b, 4096+l, :] = xs[b, 4096+l, :] + xp2[b, l, :]
__global__ __launch_bounds__(256) void add_upper(const float* __restrict__ xs, const float* __restrict__ xp2,
                                                 float* __restrict__ out)
{
  long g = (long)blockIdx.x * 256 + threadIdx.x;   // over NB*SEQ*DM/4
  int b = (int)(g >> 19);
  long rem = g & 524287;
  float4 p = ((const float4*)xp2)[g];
  long o = ((long)b * 8192 + SEQ) * 128 + rem;
  float4 x = ((const float4*)xs)[o];
  x.x += p.x; x.y += p.y; x.z += p.z; x.w += p.w;
  ((float4*)out)[o] = x;
}

extern "C" void kernel_launch(void* const* d_in, const int* in_sizes, int n_in,
                              void* d_out, int out_size, void* d_ws, size_t ws_size,
                              hipStream_t stream)
{
  const float* xs  = (const float*)d_in[0];
  const float* xd  = (const float*)d_in[1];
  const float* xp  = (const float*)d_in[2];
  const float* w0q = (const float*)d_in[3];
  const float* w0k = (const float*)d_in[4];
  const float* w0v = (const float*)d_in[5];
  const float* w0o = (const float*)d_in[6];
  const float* b0q = (const float*)d_in[7];
  const float* b0k = (const float*)d_in[8];
  const float* b0v = (const float*)d_in[9];
  const float* b0o = (const float*)d_in[10];
  const float* w1q = (const float*)d_in[11];
  const float* w1k = (const float*)d_in[12];
  const float* w1v = (const float*)d_in[13];
  const float* w1o = (const float*)d_in[14];
  const float* b1q = (const float*)d_in[15];
  const float* b1k = (const float*)d_in[16];
  const float* b1v = (const float*)d_in[17];
  const float* b1o = (const float*)d_in[18];
  float* out = (float*)d_out;

  const long BIG = (long)NB * SEQ * DM;   // 8388608 floats
  float* A  = (float*)d_ws;
  float* Bb = A  + BIG;
  float* Cc = Bb + BIG;
  float* Dd = Cc + BIG;
  float* ex = Dd + BIG;
  int*   idxbuf = (int*)ex;
  float* Mbuf   = ex + NIDX;
  int*   topidx = (int*)(Mbuf + (long)NB * NH * SEQ);
  float* vsum   = (float*)(topidx + NB * NH * UU);

  dim3 gg(128, 4);
  dim3 ag(NB * NH, NC);
  u32 k2a, k2b;

  // ---------- layer 0: xp2 = attn_layer(q=xp; kv=xd), key 42 ----------
  threefry2x32(0u, 42u, 0u, 1u, &k2a, &k2b);
  gen_idx_kernel<<<(NIDX + 255) / 256, 256, 0, stream>>>(k2a, k2b, idxbuf);
  gemm512<<<gg, 256, 0, stream>>>(xp, w0q, b0q, A,  nullptr, 0);
  gemm512<<<gg, 256, 0, stream>>>(xd, w0k, b0k, Bb, nullptr, 0);
  gemm512<<<gg, 256, 0, stream>>>(xd, w0v, b0v, Cc, nullptr, 0);
  mscore_kernel<<<NB * SEQ / 4, 256, 0, stream>>>(A, Bb, idxbuf, Mbuf);
  topk_kernel<<<NB * NH, 256, 0, stream>>>(Mbuf, topidx);
  hipMemsetAsync(vsum, 0, NB * DM * sizeof(float), stream);
  vmean_partial<<<NB * 32, 512, 0, stream>>>(Cc, vsum);
  attn_part<<<ag, 256, 0, stream>>>(A, Bb, Cc, topidx, Dd);   // partials in Dd (free in layer 0)
  ctx_fill<<<8192, 256, 0, stream>>>(vsum, A);
  attn_merge<<<NB * NH * UU, 64, 0, stream>>>(Dd, topidx, A);
  gemm512<<<gg, 256, 0, stream>>>(A, w0o, b0o, Bb, nullptr, 0);   // xp2 -> Bb
  add_upper<<<8192, 256, 0, stream>>>(xs, Bb, out);               // upper half done now

  // ---------- layer 1: xd2 = attn_layer(q=xd; kv=xp2), key 43 ----------
  threefry2x32(0u, 43u, 0u, 1u, &k2a, &k2b);
  gen_idx_kernel<<<(NIDX + 255) / 256, 256, 0, stream>>>(k2a, k2b, idxbuf);
  gemm512<<<gg, 256, 0, stream>>>(xd, w1q, b1q, A,  nullptr, 0);
  gemm512<<<gg, 256, 0, stream>>>(Bb, w1k, b1k, Cc, nullptr, 0);
  gemm512<<<gg, 256, 0, stream>>>(Bb, w1v, b1v, Dd, nullptr, 0);
  mscore_kernel<<<NB * SEQ / 4, 256, 0, stream>>>(A, Cc, idxbuf, Mbuf);
  topk_kernel<<<NB * NH, 256, 0, stream>>>(Mbuf, topidx);
  hipMemsetAsync(vsum, 0, NB * DM * sizeof(float), stream);
  vmean_partial<<<NB * 32, 512, 0, stream>>>(Dd, vsum);
  attn_part<<<ag, 256, 0, stream>>>(A, Cc, Dd, topidx, Bb);   // partials in Bb (xp2 consumed)
  ctx_fill<<<8192, 256, 0, stream>>>(vsum, A);
  attn_merge<<<NB * NH * UU, 64, 0, stream>>>(Bb, topidx, A);
  // xd2 + xs -> out[:, :4096, :]  (rowJump skips the upper half per batch)
  gemm512<<<gg, 256, 0, stream>>>(A, w1o, b1o, out, xs, SEQ * DM);
}

// Round 4
// 927.224 us; speedup vs baseline: 3.1926x; 1.5344x over previous
//
#include <hip/hip_runtime.h>
#include <math.h>

#define NB 4
#define SEQ 4096
#define DM 512
#define NH 8
#define HD 64
#define UU 27
#define NIDX (SEQ*UU)   // 110592
#define NC 32           // key chunks per (b,h) in attn_part
#define CS 128          // chunk size (keys)
#define PSTRIDE 66      // per-(bh,chunk,u) partial: m, l, acc[64]
#define LDP 40          // LDS row pitch in shorts (80 B -> conflict-free b128 frag reads)

typedef unsigned int u32;
typedef __attribute__((ext_vector_type(8))) short short8;
typedef __attribute__((ext_vector_type(4))) float f32x4;

__host__ __device__ inline u32 rotl32(u32 x, u32 r){ return (x<<r)|(x>>(32u-r)); }

// Exact JAX threefry2x32 block cipher.
__host__ __device__ inline void threefry2x32(u32 k0, u32 k1, u32 x0, u32 x1, u32* o0, u32* o1)
{
  u32 ks[3] = { k0, k1, k0 ^ k1 ^ 0x1BD11BDAu };
  x0 += ks[0]; x1 += ks[1];
  const u32 rotA[4] = {13u,15u,26u,6u};
  const u32 rotB[4] = {17u,29u,16u,24u};
  for (int i = 0; i < 5; i++) {
    const u32* rot = (i & 1) ? rotB : rotA;
    for (int j = 0; j < 4; j++) { x0 += x1; x1 = rotl32(x1, rot[j]); x1 ^= x0; }
    x0 += ks[(i+1)%3];
    x1 += ks[(i+2)%3] + (u32)(i+1);
  }
  *o0 = x0; *o1 = x1;
}

__global__ __launch_bounds__(256) void gen_idx_kernel(u32 k2a, u32 k2b, int* __restrict__ idx)
{
  int i = blockIdx.x * 256 + threadIdx.x;
  if (i >= NIDX) return;
  u32 o0, o1;
  threefry2x32(k2a, k2b, 0u, (u32)i, &o0, &o1);
  idx[i] = (int)((o0 ^ o1) & (SEQ - 1));
}

__device__ inline unsigned short f2bf_rne(float f) {
  u32 u = __float_as_uint(f);
  return (unsigned short)((u + 0x7fffu + ((u >> 16) & 1u)) >> 16);
}
// split: hi = truncation, lo = bf16(f - hi). |err| ~ 2^-17 relative.
__device__ inline void f2bf_split(float f, unsigned short& hi, unsigned short& lo) {
  u32 u = __float_as_uint(f);
  unsigned short h = (unsigned short)(u >> 16);
  float hf = __uint_as_float(((u32)h) << 16);
  hi = h;
  lo = f2bf_rne(f - hf);
}

// MFMA GEMM: C(16384,512) = A @ W + bias [+resid]; A,W fp32 in global, converted
// to bf16 (SPLIT: hi+lo, 3 MFMA products -> ~fp32 precision) during LDS staging.
// BM=BN=128, BK=32, 256 thr = 4 waves, wave does 64x64 via 4x4 16x16x32 frags.
template<int SPLIT>
__global__ __launch_bounds__(256) void gemm_mfma(
    const float* __restrict__ A, const float* __restrict__ W,
    const float* __restrict__ bias, float* __restrict__ C,
    const float* __restrict__ resid, int rowJump)
{
  __shared__ short As_hi[128 * LDP];
  __shared__ short Ws_hi[128 * LDP];
  __shared__ short As_lo[SPLIT ? 128 * LDP : 8];
  __shared__ short Ws_lo[SPLIT ? 128 * LDP : 8];

  const int t  = threadIdx.x;
  const int rb = blockIdx.x * 128;
  const int cb = blockIdx.y * 128;

  // A staging: thread -> (row, k-half of 16)
  const int sa_row = t >> 1, sa_kh = (t & 1) * 16;
  const float* Ap = A + (long)(rb + sa_row) * DM + sa_kh;
  // W staging: thread -> column n, k-block of 8 (x2 passes)
  const int sw_n = t & 127, sw_kb = t >> 7;   // kb in {0,1}, +2 on pass 2
  const float* Wp = W + cb + sw_n;

  // fragment indices
  const int lane = t & 63, wv = t >> 6;
  const int wm = (wv & 1) * 64, wn = (wv >> 1) * 64;
  const int fr = lane & 15, fq = lane >> 4;

  f32x4 acc[4][4];
  #pragma unroll
  for (int i = 0; i < 4; i++)
    #pragma unroll
    for (int j = 0; j < 4; j++) acc[i][j] = (f32x4)(0.f);

  for (int k0 = 0; k0 < DM; k0 += 32) {
    // ---- global loads (before barrier) ----
    float a_f[16];
    *(float4*)&a_f[0]  = *(const float4*)(Ap + k0);
    *(float4*)&a_f[4]  = *(const float4*)(Ap + k0 + 4);
    *(float4*)&a_f[8]  = *(const float4*)(Ap + k0 + 8);
    *(float4*)&a_f[12] = *(const float4*)(Ap + k0 + 12);
    float w_f[16];
    #pragma unroll
    for (int j = 0; j < 8; j++) w_f[j]     = Wp[(long)(k0 + sw_kb * 8 + j) * DM];
    #pragma unroll
    for (int j = 0; j < 8; j++) w_f[8 + j] = Wp[(long)(k0 + (sw_kb + 2) * 8 + j) * DM];

    __syncthreads();   // previous iteration's frag reads done

    // ---- convert + LDS write ----
    union { short8 v[2]; unsigned short s[16]; } ah, al, wh, wl;
    if (SPLIT) {
      #pragma unroll
      for (int e = 0; e < 16; e++) f2bf_split(a_f[e], ah.s[e], al.s[e]);
      #pragma unroll
      for (int e = 0; e < 16; e++) f2bf_split(w_f[e], wh.s[e], wl.s[e]);
    } else {
      #pragma unroll
      for (int e = 0; e < 16; e++) ah.s[e] = f2bf_rne(a_f[e]);
      #pragma unroll
      for (int e = 0; e < 16; e++) wh.s[e] = f2bf_rne(w_f[e]);
    }
    *(short8*)&As_hi[sa_row * LDP + sa_kh]     = ah.v[0];
    *(short8*)&As_hi[sa_row * LDP + sa_kh + 8] = ah.v[1];
    *(short8*)&Ws_hi[sw_n * LDP + sw_kb * 8]        = wh.v[0];
    *(short8*)&Ws_hi[sw_n * LDP + (sw_kb + 2) * 8]  = wh.v[1];
    if (SPLIT) {
      *(short8*)&As_lo[sa_row * LDP + sa_kh]     = al.v[0];
      *(short8*)&As_lo[sa_row * LDP + sa_kh + 8] = al.v[1];
      *(short8*)&Ws_lo[sw_n * LDP + sw_kb * 8]        = wl.v[0];
      *(short8*)&Ws_lo[sw_n * LDP + (sw_kb + 2) * 8]  = wl.v[1];
    }
    __syncthreads();

    // ---- fragments + MFMA ----
    short8 a_hi[4], b_hi[4];
    #pragma unroll
    for (int i = 0; i < 4; i++)
      a_hi[i] = *(const short8*)&As_hi[(wm + i * 16 + fr) * LDP + fq * 8];
    #pragma unroll
    for (int j = 0; j < 4; j++)
      b_hi[j] = *(const short8*)&Ws_hi[(wn + j * 16 + fr) * LDP + fq * 8];
    #pragma unroll
    for (int i = 0; i < 4; i++)
      #pragma unroll
      for (int j = 0; j < 4; j++)
        acc[i][j] = __builtin_amdgcn_mfma_f32_16x16x32_bf16(a_hi[i], b_hi[j], acc[i][j], 0, 0, 0);
    if (SPLIT) {
      short8 a_lo[4], b_lo[4];
      #pragma unroll
      for (int i = 0; i < 4; i++)
        a_lo[i] = *(const short8*)&As_lo[(wm + i * 16 + fr) * LDP + fq * 8];
      #pragma unroll
      for (int j = 0; j < 4; j++)
        b_lo[j] = *(const short8*)&Ws_lo[(wn + j * 16 + fr) * LDP + fq * 8];
      #pragma unroll
      for (int i = 0; i < 4; i++)
        #pragma unroll
        for (int j = 0; j < 4; j++) {
          acc[i][j] = __builtin_amdgcn_mfma_f32_16x16x32_bf16(a_hi[i], b_lo[j], acc[i][j], 0, 0, 0);
          acc[i][j] = __builtin_amdgcn_mfma_f32_16x16x32_bf16(a_lo[i], b_hi[j], acc[i][j], 0, 0, 0);
        }
    }
  }

  // ---- epilogue: D layout col=lane&15, row=fq*4+reg ----
  #pragma unroll
  for (int j = 0; j < 4; j++) {
    int col = cb + wn + j * 16 + fr;
    float bv = bias[col];
    #pragma unroll
    for (int i = 0; i < 4; i++) {
      int row0 = rb + wm + i * 16 + fq * 4;
      #pragma unroll
      for (int r = 0; r < 4; r++) {
        int row = row0 + r;
        long off = (long)row * DM + (long)(row >> 12) * rowJump + col;
        float v = acc[i][j][r] + bv;
        if (resid) v += resid[off];
        C[off] = v;
      }
    }
  }
}

// M[b,h,l] for ALL 8 heads by one wave per (b,l): lane = h*8+j, 8 dims/lane.
__global__ __launch_bounds__(256) void mscore_kernel(const float* __restrict__ Q, const float* __restrict__ K,
                                                     const int* __restrict__ idx, float* __restrict__ M)
{
  const int wl = threadIdx.x >> 6, lane = threadIdx.x & 63;
  const int bl = blockIdx.x * 4 + wl;       // b*4096 + l
  const int b = bl >> 12, l = bl & (SEQ - 1);

  const float4* qp = (const float4*)(Q + (long)bl * DM + lane * 8);
  float4 q0 = qp[0], q1 = qp[1];

  const int* ip = idx + l * UU;
  int idxv = ip[lane < UU ? lane : 0];

  const float* kb = K + ((long)b << 12) * DM + lane * 8;
  float mx = -INFINITY, sm = 0.f;
  #pragma unroll 4
  for (int s = 0; s < UU; s++) {
    int kl = __shfl(idxv, s, 64);
    const float4* kp = (const float4*)(kb + (long)kl * DM);
    float4 k0 = kp[0], k1 = kp[1];
    float dot;
    dot = q0.x * k0.x;
    dot = fmaf(q0.y, k0.y, dot); dot = fmaf(q0.z, k0.z, dot); dot = fmaf(q0.w, k0.w, dot);
    dot = fmaf(q1.x, k1.x, dot); dot = fmaf(q1.y, k1.y, dot);
    dot = fmaf(q1.z, k1.z, dot); dot = fmaf(q1.w, k1.w, dot);
    dot += __shfl_xor(dot, 1, 64);
    dot += __shfl_xor(dot, 2, 64);
    dot += __shfl_xor(dot, 4, 64);
    mx = fmaxf(mx, dot);
    sm += dot;
  }
  if ((lane & 7) == 0) {
    int h = lane >> 3;
    M[(((long)b * NH + h) << 12) + l] = mx - sm * (1.0f / (float)SEQ);
  }
}

// Stable top-27 of 4096 per (b,h). Ties: lower index first (lax.top_k).
__global__ __launch_bounds__(256) void topk_kernel(const float* __restrict__ M, int* __restrict__ topidx)
{
  __shared__ float vals[SEQ];
  __shared__ float rv[256];
  __shared__ int   ri[256];
  const float* m = M + (long)blockIdx.x * SEQ;
  for (int i = threadIdx.x; i < SEQ; i += 256) vals[i] = m[i];
  __syncthreads();
  for (int it = 0; it < UU; it++) {
    float bv = -INFINITY; int bi = 0x7fffffff;
    for (int i = threadIdx.x; i < SEQ; i += 256) {
      float v = vals[i];
      if (v > bv) { bv = v; bi = i; }
    }
    rv[threadIdx.x] = bv; ri[threadIdx.x] = bi;
    __syncthreads();
    for (int s = 128; s > 0; s >>= 1) {
      if (threadIdx.x < s) {
        float ov = rv[threadIdx.x + s]; int oi = ri[threadIdx.x + s];
        if (ov > rv[threadIdx.x] || (ov == rv[threadIdx.x] && oi < ri[threadIdx.x])) {
          rv[threadIdx.x] = ov; ri[threadIdx.x] = oi;
        }
      }
      __syncthreads();
    }
    if (threadIdx.x == 0) { topidx[blockIdx.x * UU + it] = ri[0]; vals[ri[0]] = -INFINITY; }
    __syncthreads();
  }
}

__global__ __launch_bounds__(512) void vmean_partial(const float* __restrict__ V, float* __restrict__ vsum)
{
  int b = blockIdx.x >> 5, chunk = blockIdx.x & 31;
  int c = threadIdx.x;
  const float* p = V + ((long)b * SEQ + chunk * 128) * DM + c;
  float s = 0.f;
  for (int l = 0; l < 128; l++) s += p[(long)l * DM];
  atomicAdd(&vsum[b * DM + c], s);
}

// Flash-style chunked attention for the 27 selected queries.
__global__ __launch_bounds__(256) void attn_part(const float* __restrict__ Q, const float* __restrict__ K,
                                                 const float* __restrict__ V, const int* __restrict__ topidx,
                                                 float* __restrict__ partial)
{
  __shared__ float Qs[UU][HD];
  __shared__ float S[UU][CS];
  __shared__ float Vt[CS][HD];
  __shared__ float m_s[UU], l_s[UU];

  const int t = threadIdx.x;
  const int bh = blockIdx.x;
  const int chunk = blockIdx.y;
  const int b = bh >> 3, h = bh & 7;
  const long kbase = ((long)(b << 12) + chunk * CS) * DM + h * HD;
  const int* tp = topidx + bh * UU;

  for (int i = t; i < UU * HD; i += 256) {
    int u = i >> 6, d = i & 63;
    Qs[u][d] = Q[((long)(b << 12) + tp[u]) * DM + h * HD + d];
  }
  for (int i = t; i < CS * (HD / 4); i += 256) {
    int row = i >> 4, c4 = (i & 15) << 2;
    *(float4*)&Vt[row][c4] = *(const float4*)(V + kbase + (long)row * DM + c4);
  }
  __syncthreads();

  {
    const int l = t >> 1, half = t & 1, d0 = half * 32;
    const float* kp = K + kbase + (long)l * DM + d0;
    float4 kr[8];
    #pragma unroll
    for (int j = 0; j < 8; j++) kr[j] = *(const float4*)(kp + j * 4);
    #pragma unroll 1
    for (int u = 0; u < UU; u++) {
      const float4* qf = (const float4*)&Qs[u][d0];
      float dot = 0.f;
      #pragma unroll
      for (int j = 0; j < 8; j++) {
        float4 q = qf[j];
        dot = fmaf(q.x, kr[j].x, dot); dot = fmaf(q.y, kr[j].y, dot);
        dot = fmaf(q.z, kr[j].z, dot); dot = fmaf(q.w, kr[j].w, dot);
      }
      float tot = dot + __shfl_xor(dot, 1, 64);
      if (half == 0) S[u][l] = tot * 0.125f;
    }
  }
  __syncthreads();

  {
    const int u = t >> 3, il = t & 7;
    if (u < UU) {
      float mx = -INFINITY;
      for (int l = il; l < CS; l += 8) mx = fmaxf(mx, S[u][l]);
      #pragma unroll
      for (int m = 1; m < 8; m <<= 1) mx = fmaxf(mx, __shfl_xor(mx, m, 64));
      float ps = 0.f;
      for (int l = il; l < CS; l += 8) {
        float e = expf(S[u][l] - mx);
        S[u][l] = e;
        ps += e;
      }
      #pragma unroll
      for (int m = 1; m < 8; m <<= 1) ps += __shfl_xor(ps, m, 64);
      if (il == 0) { m_s[u] = mx; l_s[u] = ps; }
    }
  }
  __syncthreads();

  {
    const int d = t & 63, g = t >> 6;
    for (int u = g; u < UU; u += 4) {
      float acc = 0.f;
      #pragma unroll 4
      for (int l = 0; l < CS; l += 4) {
        float4 p4 = *(const float4*)&S[u][l];
        acc = fmaf(p4.x, Vt[l][d],     acc);
        acc = fmaf(p4.y, Vt[l + 1][d], acc);
        acc = fmaf(p4.z, Vt[l + 2][d], acc);
        acc = fmaf(p4.w, Vt[l + 3][d], acc);
      }
      float* pp = partial + (((long)bh * NC + chunk) * UU + u) * PSTRIDE;
      pp[2 + d] = acc;
      if (d == 0) { pp[0] = m_s[u]; pp[1] = l_s[u]; }
    }
  }
}

__global__ __launch_bounds__(64) void attn_merge(const float* __restrict__ partial, const int* __restrict__ topidx,
                                                 float* __restrict__ ctx)
{
  int g = blockIdx.x;
  int bh = g / UU, u = g % UU;
  int b = bh >> 3, h = bh & 7;
  int d = threadIdx.x;
  float M = -INFINITY, S = 0.f, acc = 0.f;
  for (int c = 0; c < NC; c++) {
    const float* pp = partial + (((long)bh * NC + c) * UU + u) * PSTRIDE;
    float mc = pp[0], sc = pp[1], a = pp[2 + d];
    if (mc > M) {
      float r = expf(M - mc);
      acc *= r; S *= r; M = mc;
    }
    float w = expf(mc - M);
    acc = fmaf(a, w, acc);
    S = fmaf(sc, w, S);
  }
  int ql = topidx[g];
  ctx[((long)(b << 12) + ql) * DM + h * HD + d] = acc / S;
}

__global__ __launch_bounds__(256) void ctx_fill(const float* __restrict__ vsum, float* __restrict__ ctx)
{
  long g = (long)blockIdx.x * 256 + threadIdx.x;
  int b = (int)(g >> 19);
  int c4 = (int)(g & 127);
  float4 v = ((const float4*)vsum)[b * 128 + c4];
  const float s = 1.0f / (float)SEQ;
  v.x *= s; v.y *= s; v.z *= s; v.w *= s;
  ((float4*)ctx)[g] = v;
}

__global__ __launch_bounds__(256) void add_upper(const float* __restrict__ xs, const float* __restrict__ xp2,
                                                 float* __restrict__ out)
{
  long g = (long)blockIdx.x * 256 + threadIdx.x;
  int b = (int)(g >> 19);
  long rem = g & 524287;
  float4 p = ((const float4*)xp2)[g];
  long o = ((long)b * 8192 + SEQ) * 128 + rem;
  float4 x = ((const float4*)xs)[o];
  x.x += p.x; x.y += p.y; x.z += p.z; x.w += p.w;
  ((float4*)out)[o] = x;
}

extern "C" void kernel_launch(void* const* d_in, const int* in_sizes, int n_in,
                              void* d_out, int out_size, void* d_ws, size_t ws_size,
                              hipStream_t stream)
{
  const float* xs  = (const float*)d_in[0];
  const float* xd  = (const float*)d_in[1];
  const float* xp  = (const float*)d_in[2];
  const float* w0q = (const float*)d_in[3];
  const float* w0k = (const float*)d_in[4];
  const float* w0v = (const float*)d_in[5];
  const float* w0o = (const float*)d_in[6];
  const float* b0q = (const float*)d_in[7];
  const float* b0k = (const float*)d_in[8];
  const float* b0v = (const float*)d_in[9];
  const float* b0o = (const float*)d_in[10];
  const float* w1q = (const float*)d_in[11];
  const float* w1k = (const float*)d_in[12];
  const float* w1v = (const float*)d_in[13];
  const float* w1o = (const float*)d_in[14];
  const float* b1q = (const float*)d_in[15];
  const float* b1k = (const float*)d_in[16];
  const float* b1v = (const float*)d_in[17];
  const float* b1o = (const float*)d_in[18];
  float* out = (float*)d_out;

  const long BIG = (long)NB * SEQ * DM;
  float* A  = (float*)d_ws;
  float* Bb = A  + BIG;
  float* Cc = Bb + BIG;
  float* Dd = Cc + BIG;
  float* ex = Dd + BIG;
  int*   idxbuf = (int*)ex;
  float* Mbuf   = ex + NIDX;
  int*   topidx = (int*)(Mbuf + (long)NB * NH * SEQ);
  float* vsum   = (float*)(topidx + NB * NH * UU);

  dim3 gg(128, 4);
  dim3 ag(NB * NH, NC);
  u32 k2a, k2b;

  // ---------- layer 0: xp2 = attn_layer(q=xp; kv=xd), key 42 ----------
  threefry2x32(0u, 42u, 0u, 1u, &k2a, &k2b);
  gen_idx_kernel<<<(NIDX + 255) / 256, 256, 0, stream>>>(k2a, k2b, idxbuf);
  gemm_mfma<1><<<gg, 256, 0, stream>>>(xp, w0q, b0q, A,  nullptr, 0);
  gemm_mfma<1><<<gg, 256, 0, stream>>>(xd, w0k, b0k, Bb, nullptr, 0);
  gemm_mfma<1><<<gg, 256, 0, stream>>>(xd, w0v, b0v, Cc, nullptr, 0);
  mscore_kernel<<<NB * SEQ / 4, 256, 0, stream>>>(A, Bb, idxbuf, Mbuf);
  topk_kernel<<<NB * NH, 256, 0, stream>>>(Mbuf, topidx);
  hipMemsetAsync(vsum, 0, NB * DM * sizeof(float), stream);
  vmean_partial<<<NB * 32, 512, 0, stream>>>(Cc, vsum);
  attn_part<<<ag, 256, 0, stream>>>(A, Bb, Cc, topidx, Dd);
  ctx_fill<<<8192, 256, 0, stream>>>(vsum, A);
  attn_merge<<<NB * NH * UU, 64, 0, stream>>>(Dd, topidx, A);
  gemm_mfma<1><<<gg, 256, 0, stream>>>(A, w0o, b0o, Bb, nullptr, 0);   // xp2 (feeds L1 top-k): split
  add_upper<<<8192, 256, 0, stream>>>(xs, Bb, out);

  // ---------- layer 1: xd2 = attn_layer(q=xd; kv=xp2), key 43 ----------
  threefry2x32(0u, 43u, 0u, 1u, &k2a, &k2b);
  gen_idx_kernel<<<(NIDX + 255) / 256, 256, 0, stream>>>(k2a, k2b, idxbuf);
  gemm_mfma<1><<<gg, 256, 0, stream>>>(xd, w1q, b1q, A,  nullptr, 0);
  gemm_mfma<1><<<gg, 256, 0, stream>>>(Bb, w1k, b1k, Cc, nullptr, 0);
  gemm_mfma<0><<<gg, 256, 0, stream>>>(Bb, w1v, b1v, Dd, nullptr, 0);  // value path: plain bf16
  mscore_kernel<<<NB * SEQ / 4, 256, 0, stream>>>(A, Cc, idxbuf, Mbuf);
  topk_kernel<<<NB * NH, 256, 0, stream>>>(Mbuf, topidx);
  hipMemsetAsync(vsum, 0, NB * DM * sizeof(float), stream);
  vmean_partial<<<NB * 32, 512, 0, stream>>>(Dd, vsum);
  attn_part<<<ag, 256, 0, stream>>>(A, Cc, Dd, topidx, Bb);
  ctx_fill<<<8192, 256, 0, stream>>>(vsum, A);
  attn_merge<<<NB * NH * UU, 64, 0, stream>>>(Bb, topidx, A);
  gemm_mfma<0><<<gg, 256, 0, stream>>>(A, w1o, b1o, out, xs, SEQ * DM); // value path: plain bf16
}